// Round 1
// baseline (297.242 us; speedup 1.0000x reference)
//
#include <hip/hip_runtime.h>
#include <hip/hip_fp16.h>

#define HDIM 256
#define MS 16
#define PAD 8
#define LDAK (HDIM + PAD)   // 264 halves per row, 528 B (stride = 4 banks -> conflict-free-ish)

typedef _Float16 half8 __attribute__((ext_vector_type(8)));
typedef float f32x4 __attribute__((ext_vector_type(4)));

// Pack W1,W2,W3 (fp32 [256][256], row=k, col=n) into f16 B-fragment layout:
// Wp[l][ ((k>>3)*256 + n)*8 + (k&7) ]  so a lane's 8 k-values for fixed n are one 16B load.
__global__ __launch_bounds__(256) void pack_weights(const float* __restrict__ W1,
                                                    const float* __restrict__ W2,
                                                    const float* __restrict__ W3,
                                                    _Float16* __restrict__ out) {
    int tid = blockIdx.x * blockDim.x + threadIdx.x;  // 0..196607
    int l = tid >> 16;
    int idx = tid & 65535;      // k*256 + n
    int k = idx >> 8;
    int n = idx & 255;
    const float* W = (l == 0) ? W1 : (l == 1) ? W2 : W3;
    out[l * 65536 + (((k >> 3) << 8) + n) * 8 + (k & 7)] = (_Float16)W[idx];
}

__global__ __launch_bounds__(256)
void pinn_fused(const float* __restrict__ x,
                const float* __restrict__ W0,
                const float* __restrict__ b0,
                const float* __restrict__ b1,
                const float* __restrict__ b2,
                const float* __restrict__ b3,
                const float* __restrict__ Wout,
                const float* __restrict__ bout,
                const _Float16* __restrict__ Wp,
                float* __restrict__ out) {
    // A: stacked [7 channels x 16 samples] x 256, f16, padded
    __shared__ __align__(16) _Float16 Abuf[7 * MS][LDAK];
    __shared__ float xs[MS * 3];

    const int tid  = threadIdx.x;
    const int lane = tid & 63;
    const int wid  = tid >> 6;        // wave id 0..3 -> N-strip base wid*64
    const int qd   = lane >> 4;       // quad 0..3
    const int n15  = lane & 15;
    const int base = blockIdx.x * MS; // sample base

    if (tid < MS * 3) xs[tid] = x[base * 3 + tid];
    __syncthreads();

    // ---------------- layer 0: 3 -> 256, jets initialized analytically ----------------
    #pragma unroll
    for (int t = 0; t < 4; ++t) {
        const int n = wid * 64 + t * 16 + n15;
        const float w0 = W0[0 * HDIM + n];
        const float w1 = W0[1 * HDIM + n];
        const float w2 = W0[2 * HDIM + n];
        const float bb = b0[n];
        #pragma unroll
        for (int r = 0; r < 4; ++r) {
            const int m = qd * 4 + r;
            float z  = xs[m*3+0]*w0 + xs[m*3+1]*w1 + xs[m*3+2]*w2 + bb;
            float tv = tanhf(z);
            float dd = 1.f - tv * tv;
            float c2 = -2.f * tv * dd;
            Abuf[0*MS+m][n] = (_Float16)tv;
            Abuf[1*MS+m][n] = (_Float16)(dd * w0);
            Abuf[2*MS+m][n] = (_Float16)(dd * w1);
            Abuf[3*MS+m][n] = (_Float16)(dd * w2);
            Abuf[4*MS+m][n] = (_Float16)(c2 * w0 * w0);
            Abuf[5*MS+m][n] = (_Float16)(c2 * w1 * w1);
            Abuf[6*MS+m][n] = (_Float16)(c2 * w2 * w2);
        }
    }
    __syncthreads();

    // ---------------- layers 1..3: 256 -> 256 via MFMA on stacked [112 x 256] ----------------
    #pragma unroll
    for (int l = 0; l < 3; ++l) {
        const _Float16* W = Wp + l * 65536;
        const float* bb = (l == 0) ? b1 : (l == 1) ? b2 : b3;

        f32x4 acc[7][4];
        #pragma unroll
        for (int c = 0; c < 7; ++c)
            #pragma unroll
            for (int t = 0; t < 4; ++t) acc[c][t] = (f32x4){0.f, 0.f, 0.f, 0.f};

        #pragma unroll
        for (int s = 0; s < 8; ++s) {
            half8 bf[4];
            #pragma unroll
            for (int t = 0; t < 4; ++t) {
                const int n = wid * 64 + t * 16 + n15;
                bf[t] = *(const half8*)(W + ((s * 4 + qd) * 256 + n) * 8);
            }
            #pragma unroll
            for (int c = 0; c < 7; ++c) {
                half8 af = *(const half8*)&Abuf[c * MS + n15][s * 32 + qd * 8];
                #pragma unroll
                for (int t = 0; t < 4; ++t)
                    acc[c][t] = __builtin_amdgcn_mfma_f32_16x16x32_f16(af, bf[t], acc[c][t], 0, 0, 0);
            }
        }
        __syncthreads();  // all waves done reading Abuf

        // elementwise jet update, fully in-register per (m,n)
        #pragma unroll
        for (int t = 0; t < 4; ++t) {
            const int n = wid * 64 + t * 16 + n15;
            const float bias = bb[n];
            #pragma unroll
            for (int r = 0; r < 4; ++r) {
                const int m = qd * 4 + r;
                float zv = acc[0][t][r] + bias;
                float tv = tanhf(zv);
                float dd = 1.f - tv * tv;
                float c2 = -2.f * tv * dd;
                Abuf[0*MS+m][n] = (_Float16)tv;
                #pragma unroll
                for (int i = 0; i < 3; ++i) {
                    float zg = acc[1 + i][t][r];
                    float zs = acc[4 + i][t][r];
                    Abuf[(1+i)*MS+m][n] = (_Float16)(dd * zg);
                    Abuf[(4+i)*MS+m][n] = (_Float16)(dd * zs + c2 * zg * zg);
                }
            }
        }
        __syncthreads();
    }

    // ---------------- output layer: 7*16 = 112 dot products of length 256 ----------------
    if (tid < 7 * MS) {
        const int c = tid >> 4;
        const int m = tid & 15;
        const _Float16* row = Abuf[tid];  // c*MS + m == tid
        float accv = 0.f;
        #pragma unroll 4
        for (int k = 0; k < HDIM; k += 8) {
            half8 av = *(const half8*)&row[k];
            #pragma unroll
            for (int j = 0; j < 8; ++j) accv += (float)av[j] * Wout[k + j];
        }
        if (c == 0) accv += bout[0];
        out[(base + m) * 7 + c] = accv;
    }
}

extern "C" void kernel_launch(void* const* d_in, const int* in_sizes, int n_in,
                              void* d_out, int out_size, void* d_ws, size_t ws_size,
                              hipStream_t stream) {
    const float* xp   = (const float*)d_in[0];
    const float* W0   = (const float*)d_in[1];
    const float* b0   = (const float*)d_in[2];
    const float* W1   = (const float*)d_in[3];
    const float* b1   = (const float*)d_in[4];
    const float* W2   = (const float*)d_in[5];
    const float* b2   = (const float*)d_in[6];
    const float* W3   = (const float*)d_in[7];
    const float* b3   = (const float*)d_in[8];
    const float* Wout = (const float*)d_in[9];
    const float* bout = (const float*)d_in[10];
    _Float16* Wp = (_Float16*)d_ws;  // 3 * 65536 halves = 384 KB

    pack_weights<<<768, 256, 0, stream>>>(W1, W2, W3, Wp);
    pinn_fused<<<65536 / MS, 256, 0, stream>>>(xp, W0, b0, b1, b2, b3, Wout, bout, Wp,
                                               (float*)d_out);
}

// Round 2
// 267.816 us; speedup vs baseline: 1.1099x; 1.1099x over previous
//
#include <hip/hip_runtime.h>
#include <hip/hip_fp16.h>

#define HDIM 256
#define MS 16
#define PAD 8
#define LDAK (HDIM + PAD)   // 264 halves per row

typedef _Float16 half8 __attribute__((ext_vector_type(8)));
typedef _Float16 half4 __attribute__((ext_vector_type(4)));
typedef float f32x4 __attribute__((ext_vector_type(4)));

__device__ __forceinline__ float fast_tanh(float x) {
    // tanh(x) = 1 - 2/(e^{2x}+1); v_exp-based, graceful at +-inf
    float e = __expf(2.0f * x);
    return 1.0f - 2.0f * __builtin_amdgcn_rcpf(e + 1.0f);
}

// Pack W1,W2,W3 (fp32 [256][256], row=k, col=n) into f16 frag layout:
// Wp[l][ ((k>>3)*256 + n)*8 + (k&7) ]  -> one 16B load per lane-frag.
__global__ __launch_bounds__(256) void pack_weights(const float* __restrict__ W1,
                                                    const float* __restrict__ W2,
                                                    const float* __restrict__ W3,
                                                    _Float16* __restrict__ out) {
    int tid = blockIdx.x * blockDim.x + threadIdx.x;  // 0..196607
    int l = tid >> 16;
    int idx = tid & 65535;      // k*256 + n
    int k = idx >> 8;
    int n = idx & 255;
    const float* W = (l == 0) ? W1 : (l == 1) ? W2 : W3;
    out[l * 65536 + (((k >> 3) << 8) + n) * 8 + (k & 7)] = (_Float16)W[idx];
}

__global__ __launch_bounds__(256, 2)
void pinn_fused(const float* __restrict__ x,
                const float* __restrict__ W0,
                const float* __restrict__ b0,
                const float* __restrict__ b1,
                const float* __restrict__ b2,
                const float* __restrict__ b3,
                const float* __restrict__ Wout,
                const float* __restrict__ bout,
                const _Float16* __restrict__ Wp,
                float* __restrict__ out) {
    // A: stacked [7 channels x 16 samples] rows x 256 k, f16, padded
    __shared__ __align__(16) _Float16 Abuf[7 * MS][LDAK];
    __shared__ float xs[MS * 3];

    const int tid  = threadIdx.x;
    const int lane = tid & 63;
    const int wid  = tid >> 6;        // wave id 0..3 -> n-strip base wid*64
    const int qd   = lane >> 4;       // quad 0..3
    const int n15  = lane & 15;
    const int base = blockIdx.x * MS; // sample base

    if (tid < MS * 3) xs[tid] = x[base * 3 + tid];
    __syncthreads();

    // ---------------- layer 0: 3 -> 256, jets analytic; b64 writes ----------------
    {
        const int m = tid & 15;
        const int n0base = (tid >> 4) * 16;   // 16 consecutive n per thread
        const float x0 = xs[m * 3 + 0], x1 = xs[m * 3 + 1], x2 = xs[m * 3 + 2];
        #pragma unroll
        for (int ch = 0; ch < 4; ++ch) {
            const int n0 = n0base + ch * 4;
            f32x4 w0 = *(const f32x4*)(W0 + 0 * HDIM + n0);
            f32x4 w1 = *(const f32x4*)(W0 + 1 * HDIM + n0);
            f32x4 w2 = *(const f32x4*)(W0 + 2 * HDIM + n0);
            f32x4 bv = *(const f32x4*)(b0 + n0);
            half4 h[7];
            #pragma unroll
            for (int r = 0; r < 4; ++r) {
                float z  = x0 * w0[r] + x1 * w1[r] + x2 * w2[r] + bv[r];
                float tv = fast_tanh(z);
                float dd = 1.f - tv * tv;
                float c2 = -2.f * tv * dd;
                h[0][r] = (_Float16)tv;
                h[1][r] = (_Float16)(dd * w0[r]);
                h[2][r] = (_Float16)(dd * w1[r]);
                h[3][r] = (_Float16)(dd * w2[r]);
                h[4][r] = (_Float16)(c2 * w0[r] * w0[r]);
                h[5][r] = (_Float16)(c2 * w1[r] * w1[r]);
                h[6][r] = (_Float16)(c2 * w2[r] * w2[r]);
            }
            #pragma unroll
            for (int c = 0; c < 7; ++c)
                *(half4*)&Abuf[c * MS + m][n0] = h[c];
        }
    }
    __syncthreads();

    // ---------------- layers 1..3: transposed MFMA (Z^T = W^T A^T) ----------------
    #pragma unroll
    for (int l = 0; l < 3; ++l) {
        const _Float16* W = Wp + l * 65536;
        const float* bb = (l == 0) ? b1 : (l == 1) ? b2 : b3;

        f32x4 acc[7][4];
        #pragma unroll
        for (int c = 0; c < 7; ++c)
            #pragma unroll
            for (int t = 0; t < 4; ++t) acc[c][t] = (f32x4){0.f, 0.f, 0.f, 0.f};

        #pragma unroll
        for (int s = 0; s < 8; ++s) {
            half8 wf[4];
            #pragma unroll
            for (int t = 0; t < 4; ++t) {
                const int n = wid * 64 + t * 16 + n15;
                wf[t] = *(const half8*)(W + ((s * 4 + qd) * 256 + n) * 8);
            }
            #pragma unroll
            for (int c = 0; c < 7; ++c) {
                half8 af = *(const half8*)&Abuf[c * MS + n15][s * 32 + qd * 8];
                #pragma unroll
                for (int t = 0; t < 4; ++t)
                    acc[c][t] = __builtin_amdgcn_mfma_f32_16x16x32_f16(wf[t], af, acc[c][t], 0, 0, 0);
            }
        }
        __syncthreads();  // all waves done reading Abuf

        // lane holds Z[m = n15][n = wid*64 + t*16 + qd*4 + r] for r=0..3
        #pragma unroll
        for (int t = 0; t < 4; ++t) {
            const int ncol = wid * 64 + t * 16 + qd * 4;
            f32x4 bv = *(const f32x4*)(bb + ncol);
            half4 h[7];
            #pragma unroll
            for (int r = 0; r < 4; ++r) {
                float zv = acc[0][t][r] + bv[r];
                float tv = fast_tanh(zv);
                float dd = 1.f - tv * tv;
                float c2 = -2.f * tv * dd;
                h[0][r] = (_Float16)tv;
                #pragma unroll
                for (int i = 0; i < 3; ++i) {
                    float zg = acc[1 + i][t][r];
                    float zs = acc[4 + i][t][r];
                    h[1 + i][r] = (_Float16)(dd * zg);
                    h[4 + i][r] = (_Float16)(dd * zs + c2 * zg * zg);
                }
            }
            #pragma unroll
            for (int c = 0; c < 7; ++c)
                *(half4*)&Abuf[c * MS + n15][ncol] = h[c];
        }
        __syncthreads();
    }

    // ---------------- output: 112 rows x 256 dot Wout; 224 threads, pair-reduce ----------------
    if (tid < 7 * MS * 2) {
        const int row = tid >> 1;        // 0..111
        const int h   = tid & 1;
        const _Float16* rp = &Abuf[row][h * 128];
        const float* wp = Wout + h * 128;
        float accv = 0.f;
        #pragma unroll 4
        for (int k = 0; k < 128; k += 8) {
            half8 av = *(const half8*)&rp[k];
            #pragma unroll
            for (int j = 0; j < 8; ++j) accv += (float)av[j] * wp[k + j];
        }
        accv += __shfl_xor(accv, 1, 64);
        if (h == 0) {
            const int c = row >> 4;
            const int m = row & 15;
            if (c == 0) accv += bout[0];
            out[(base + m) * 7 + c] = accv;
        }
    }
}

extern "C" void kernel_launch(void* const* d_in, const int* in_sizes, int n_in,
                              void* d_out, int out_size, void* d_ws, size_t ws_size,
                              hipStream_t stream) {
    const float* xp   = (const float*)d_in[0];
    const float* W0   = (const float*)d_in[1];
    const float* b0   = (const float*)d_in[2];
    const float* W1   = (const float*)d_in[3];
    const float* b1   = (const float*)d_in[4];
    const float* W2   = (const float*)d_in[5];
    const float* b2   = (const float*)d_in[6];
    const float* W3   = (const float*)d_in[7];
    const float* b3   = (const float*)d_in[8];
    const float* Wout = (const float*)d_in[9];
    const float* bout = (const float*)d_in[10];
    _Float16* Wp = (_Float16*)d_ws;  // 3 * 65536 halves = 384 KB

    pack_weights<<<768, 256, 0, stream>>>(W1, W2, W3, Wp);
    pinn_fused<<<65536 / MS, 256, 0, stream>>>(xp, W0, b0, b1, b2, b3, Wout, bout, Wp,
                                               (float*)d_out);
}